// Round 4
// baseline (344.139 us; speedup 1.0000x reference)
//
#include <hip/hip_runtime.h>
#include <math.h>

typedef __attribute__((ext_vector_type(8))) short short8;
typedef __attribute__((ext_vector_type(4))) float f32x4;

#define D 160
#define NTOK (256*512)   // 131072 rows
#define ROWS 64          // rows per block == one wave, 4 row-tiles of 16

__device__ __forceinline__ short f2bf(float f) {
  union { float f; unsigned u; } v; v.f = f;
  return (short)((v.u + 0x8000u) >> 16);   // round-half-up (=RNE except exact ties)
}

// bf16 eta tile: 64 rows x 160 cols, row stride 192 shorts (24 granules of 16B).
// XOR low 3 bits of granule index with row&7 -> 2-way max bank aliasing (free).
__device__ __forceinline__ int eidx(int row, int col) {
  int g = col >> 3;
  g = (g & ~7) | ((g ^ (row & 7)) & 7);
  return row * 192 + (g << 3) + (col & 7);
}

// Pack weights to bf16 in MFMA B-FRAGMENT ORDER (unchanged):
//   frag f = ks*10 + nt;  element (f, lane, j) = W[n][k],
//   n = nt*16 + (lane&15), k = ks*32 + (lane>>4)*8 + j.
__global__ __launch_bounds__(256) void prep_kernel(
    const float* __restrict__ W2, const float* __restrict__ W3,
    const float* __restrict__ W1, const float* __restrict__ W4,
    const float* __restrict__ W5, short* __restrict__ ws) {
  int i = blockIdx.x * 256 + threadIdx.x;
  if (i >= 128000) return;
  if (i < 51200) {
    int f = i >> 9, r = i & 511;
    int lane = r >> 3, j = r & 7;
    int ks = f / 10, nt = f % 10;
    int n = nt * 16 + (lane & 15);
    int k = ks * 32 + (lane >> 4) * 8 + j;
    float v = (k < 160) ? W2[n * 160 + k] : W3[n * 160 + (k - 160)];
    ws[i] = f2bf(v);
  } else {
    int idx = i - 51200;
    int which = idx / 25600;      // 0=W1, 1=W4, 2=W5
    int e = idx % 25600;
    int f = e >> 9, r = e & 511;
    int lane = r >> 3, j = r & 7;
    int ks = f / 10, nt = f % 10;
    int n = nt * 16 + (lane & 15);
    int k = ks * 32 + (lane >> 4) * 8 + j;
    const float* W = (which == 0) ? W1 : (which == 1) ? W4 : W5;
    ws[i] = f2bf(W[n * 160 + k]);
  }
}

#define MFMA(d, a, b) d = __builtin_amdgcn_mfma_f32_16x16x32_bf16(a, b, d, 0, 0, 0)

// One wave, 64 rows, no barriers. Each B-fragment batch (10 loads) feeds 40
// MFMAs (4 row-tiles) ~200 cyc, covering its own L2 latency; weight traffic
// amortized 4x vs the 16-row structure. Latency hiding is ILP, not TLP:
// launch_bounds(64,1) -> up to 512 VGPRs, ~1 wave/SIMD.
__global__ __launch_bounds__(64, 1) void grn_main(
    const float* __restrict__ x, const float* __restrict__ c,
    const short* __restrict__ wcatf, const short* __restrict__ w1f,
    const short* __restrict__ w4f, const short* __restrict__ w5f,
    const float* __restrict__ b2, const float* __restrict__ b1,
    const float* __restrict__ b4, const float* __restrict__ b5,
    const float* __restrict__ gamma, const float* __restrict__ beta,
    float* __restrict__ out) {
  __shared__ __align__(16) short E[ROWS * 192];   // 24576 B

  const int lane = threadIdx.x;     // 0..63
  const int lr   = lane & 15;
  const int quad = lane >> 4;
  const int rowbase = blockIdx.x * ROWS;

  size_t aoff[4];
#pragma unroll
  for (int rt = 0; rt < 4; ++rt)
    aoff[rt] = (size_t)(rowbase + rt * 16 + lr) * D + quad * 8;

  const short* wp  = wcatf + lane * 8;
  const short* wp1 = w1f + lane * 8;
  const short* wp4 = w4f + lane * 8;
  const short* wp5 = w5f + lane * 8;

  // ---------------- phase 1: eta2 = ELU([x|c] @ wcat^T + b2) ----------------
  {
    f32x4 acc[4][10];
#pragma unroll
    for (int rt = 0; rt < 4; ++rt)
#pragma unroll
      for (int nt = 0; nt < 10; ++nt) acc[rt][nt] = (f32x4){0.f, 0.f, 0.f, 0.f};

    short8 bf[10], bn[10];
#pragma unroll
    for (int nt = 0; nt < 10; ++nt) bf[nt] = *(const short8*)(wp + (nt << 9));

    // A staging: 2 ks-batches in flight (x for ks=0,1)
    f32x4 sLo[2][4], sHi[2][4];
#pragma unroll
    for (int p = 0; p < 2; ++p)
#pragma unroll
      for (int rt = 0; rt < 4; ++rt) {
        const float* ap = x + aoff[rt] + p * 32;
        sLo[p][rt] = *(const f32x4*)ap;
        sHi[p][rt] = *(const f32x4*)(ap + 4);
      }
    float b2s[10];
#pragma unroll
    for (int nt = 0; nt < 10; ++nt) b2s[nt] = b2[nt * 16 + lr];

#pragma unroll
    for (int ks = 0; ks < 10; ++ks) {
      // consume staged A(ks)
      short8 af[4];
#pragma unroll
      for (int rt = 0; rt < 4; ++rt)
#pragma unroll
        for (int j = 0; j < 4; ++j) {
          af[rt][j]     = f2bf(sLo[ks & 1][rt][j]);
          af[rt][4 + j] = f2bf(sHi[ks & 1][rt][j]);
        }
      // refill the just-freed slot with A(ks+2)
      if (ks < 8) {
#pragma unroll
        for (int rt = 0; rt < 4; ++rt) {
          const float* ap = ((ks + 2) < 5) ? (x + aoff[rt] + (ks + 2) * 32)
                                           : (c + aoff[rt] + (ks + 2 - 5) * 32);
          sLo[ks & 1][rt] = *(const f32x4*)ap;
          sHi[ks & 1][rt] = *(const f32x4*)(ap + 4);
        }
      }
      // B prefetch for ks+1
      if (ks < 9) {
#pragma unroll
        for (int nt = 0; nt < 10; ++nt)
          bn[nt] = *(const short8*)(wp + (((ks + 1) * 10 + nt) << 9));
      }
      // 40 MFMAs on this batch
#pragma unroll
      for (int nt = 0; nt < 10; ++nt)
#pragma unroll
        for (int rt = 0; rt < 4; ++rt)
          MFMA(acc[rt][nt], af[rt], bf[nt]);
#pragma unroll
      for (int nt = 0; nt < 10; ++nt)
        if (ks < 9) bf[nt] = bn[nt];
    }

#pragma unroll
    for (int rt = 0; rt < 4; ++rt)
#pragma unroll
      for (int nt = 0; nt < 10; ++nt)
#pragma unroll
        for (int r = 0; r < 4; ++r) {
          float v = acc[rt][nt][r] + b2s[nt];
          v = v > 0.f ? v : (__expf(v) - 1.f);   // ELU
          E[eidx(rt * 16 + quad * 4 + r, nt * 16 + lr)] = f2bf(v);
        }
  }

  // ---------------- phase 2: eta1 = eta2 @ W1^T + b1 (in-place) -------------
  {
    f32x4 acc[4][10];
#pragma unroll
    for (int rt = 0; rt < 4; ++rt)
#pragma unroll
      for (int nt = 0; nt < 10; ++nt) acc[rt][nt] = (f32x4){0.f, 0.f, 0.f, 0.f};
    float b1s[10];
#pragma unroll
    for (int nt = 0; nt < 10; ++nt) b1s[nt] = b1[nt * 16 + lr];

    short8 bf[10], bn[10];
#pragma unroll
    for (int nt = 0; nt < 10; ++nt) bf[nt] = *(const short8*)(wp1 + (nt << 9));
    short8 af[4], afn[4];
#pragma unroll
    for (int rt = 0; rt < 4; ++rt)
      af[rt] = *(const short8*)&E[eidx(rt * 16 + lr, quad * 8)];

#pragma unroll
    for (int ks = 0; ks < 5; ++ks) {
      if (ks < 4) {
#pragma unroll
        for (int rt = 0; rt < 4; ++rt)
          afn[rt] = *(const short8*)&E[eidx(rt * 16 + lr, (ks + 1) * 32 + quad * 8)];
#pragma unroll
        for (int nt = 0; nt < 10; ++nt)
          bn[nt] = *(const short8*)(wp1 + (((ks + 1) * 10 + nt) << 9));
      }
#pragma unroll
      for (int nt = 0; nt < 10; ++nt)
#pragma unroll
        for (int rt = 0; rt < 4; ++rt)
          MFMA(acc[rt][nt], af[rt], bf[nt]);
      if (ks < 4) {
#pragma unroll
        for (int rt = 0; rt < 4; ++rt) af[rt] = afn[rt];
#pragma unroll
        for (int nt = 0; nt < 10; ++nt) bf[nt] = bn[nt];
      }
    }

#pragma unroll
    for (int rt = 0; rt < 4; ++rt)
#pragma unroll
      for (int nt = 0; nt < 10; ++nt)
#pragma unroll
        for (int r = 0; r < 4; ++r) {
          float v = acc[rt][nt][r] + b1s[nt];
          E[eidx(rt * 16 + quad * 4 + r, nt * 16 + lr)] = f2bf(v);
        }
  }

  // ---------------- phase 3: GLU + residual, N split in two halves ----------
  float yv[2][4][5][4];             // y values carried to the LN store
  float sum[4][4], ssq[4][4];
#pragma unroll
  for (int rt = 0; rt < 4; ++rt)
#pragma unroll
    for (int r = 0; r < 4; ++r) { sum[rt][r] = 0.f; ssq[rt][r] = 0.f; }

#pragma unroll
  for (int h = 0; h < 2; ++h) {
    f32x4 ag[4][5], av[4][5];
#pragma unroll
    for (int rt = 0; rt < 4; ++rt)
#pragma unroll
      for (int nt = 0; nt < 5; ++nt) {
        ag[rt][nt] = (f32x4){0.f, 0.f, 0.f, 0.f};
        av[rt][nt] = (f32x4){0.f, 0.f, 0.f, 0.f};
      }
    float b4s[5], b5s[5];
#pragma unroll
    for (int nt = 0; nt < 5; ++nt) {
      b4s[nt] = b4[(h * 5 + nt) * 16 + lr];
      b5s[nt] = b5[(h * 5 + nt) * 16 + lr];
    }
    short8 af[4], afn[4];
#pragma unroll
    for (int rt = 0; rt < 4; ++rt)
      af[rt] = *(const short8*)&E[eidx(rt * 16 + lr, quad * 8)];

    // single-buffered B frags (gate batch covers value-batch latency and
    // vice versa); keeps peak VGPR under the 512 budget.
#pragma unroll
    for (int ks = 0; ks < 5; ++ks) {
      short8 bg[5], bv[5];
#pragma unroll
      for (int nt = 0; nt < 5; ++nt) {
        bg[nt] = *(const short8*)(wp4 + ((ks * 10 + h * 5 + nt) << 9));
        bv[nt] = *(const short8*)(wp5 + ((ks * 10 + h * 5 + nt) << 9));
      }
      if (ks < 4) {
#pragma unroll
        for (int rt = 0; rt < 4; ++rt)
          afn[rt] = *(const short8*)&E[eidx(rt * 16 + lr, (ks + 1) * 32 + quad * 8)];
      }
#pragma unroll
      for (int nt = 0; nt < 5; ++nt)
#pragma unroll
        for (int rt = 0; rt < 4; ++rt)
          MFMA(ag[rt][nt], af[rt], bg[nt]);
#pragma unroll
      for (int nt = 0; nt < 5; ++nt)
#pragma unroll
        for (int rt = 0; rt < 4; ++rt)
          MFMA(av[rt][nt], af[rt], bv[nt]);
      if (ks < 4) {
#pragma unroll
        for (int rt = 0; rt < 4; ++rt) af[rt] = afn[rt];
      }
    }

    // epilogue: residual reload first (latency hides under GLU VALU work)
    float xr[4][5][4];
#pragma unroll
    for (int rt = 0; rt < 4; ++rt)
#pragma unroll
      for (int nt = 0; nt < 5; ++nt)
#pragma unroll
        for (int r = 0; r < 4; ++r)
          xr[rt][nt][r] = x[(size_t)(rowbase + rt * 16 + quad * 4 + r) * D
                            + (h * 5 + nt) * 16 + lr];
#pragma unroll
    for (int rt = 0; rt < 4; ++rt)
#pragma unroll
      for (int nt = 0; nt < 5; ++nt)
#pragma unroll
        for (int r = 0; r < 4; ++r) {
          float g = ag[rt][nt][r] + b4s[nt];
          float v = av[rt][nt][r] + b5s[nt];
          float glu = v * __builtin_amdgcn_rcpf(1.f + __expf(-g));
          float y = xr[rt][nt][r] + glu;
          yv[h][rt][nt][r] = y;
          sum[rt][r] += y;
          ssq[rt][r] += y * y;
        }
  }

  // ---------------- LN: reduce across the 16 lanes sharing each row ---------
#pragma unroll
  for (int off = 1; off < 16; off <<= 1)
#pragma unroll
    for (int rt = 0; rt < 4; ++rt)
#pragma unroll
      for (int r = 0; r < 4; ++r) {
        sum[rt][r] += __shfl_xor(sum[rt][r], off, 64);
        ssq[rt][r] += __shfl_xor(ssq[rt][r], off, 64);
      }
  float mean[4][4], rstd[4][4];
#pragma unroll
  for (int rt = 0; rt < 4; ++rt)
#pragma unroll
    for (int r = 0; r < 4; ++r) {
      mean[rt][r] = sum[rt][r] * (1.f / 160.f);
      float var = ssq[rt][r] * (1.f / 160.f) - mean[rt][r] * mean[rt][r];
      rstd[rt][r] = __builtin_amdgcn_rsqf(var + 1e-5f);
    }

  float gs[2][5], bs[2][5];
#pragma unroll
  for (int h = 0; h < 2; ++h)
#pragma unroll
    for (int nt = 0; nt < 5; ++nt) {
      gs[h][nt] = gamma[(h * 5 + nt) * 16 + lr];
      bs[h][nt] = beta[(h * 5 + nt) * 16 + lr];
    }

#pragma unroll
  for (int h = 0; h < 2; ++h)
#pragma unroll
    for (int rt = 0; rt < 4; ++rt)
#pragma unroll
      for (int nt = 0; nt < 5; ++nt)
#pragma unroll
        for (int r = 0; r < 4; ++r) {
          size_t row = (size_t)(rowbase + rt * 16 + quad * 4 + r);
          out[row * D + (h * 5 + nt) * 16 + lr] =
              (yv[h][rt][nt][r] - mean[rt][r]) * rstd[rt][r] * gs[h][nt] + bs[h][nt];
        }
}

extern "C" void kernel_launch(void* const* d_in, const int* in_sizes, int n_in,
                              void* d_out, int out_size, void* d_ws, size_t ws_size,
                              hipStream_t stream) {
  const float* x     = (const float*)d_in[0];
  const float* c     = (const float*)d_in[1];
  const float* W2    = (const float*)d_in[2];
  const float* b2    = (const float*)d_in[3];
  const float* W3    = (const float*)d_in[4];
  const float* W1    = (const float*)d_in[5];
  const float* b1    = (const float*)d_in[6];
  const float* W4    = (const float*)d_in[7];
  const float* b4    = (const float*)d_in[8];
  const float* W5    = (const float*)d_in[9];
  const float* b5    = (const float*)d_in[10];
  const float* gamma = (const float*)d_in[11];
  const float* beta  = (const float*)d_in[12];

  short* ws = (short*)d_ws;   // 256000 B; re-packed every launch
  prep_kernel<<<500, 256, 0, stream>>>(W2, W3, W1, W4, W5, ws);

  const short* wcatf = ws;
  const short* w1f   = ws + 51200;
  const short* w4f   = w1f + 25600;
  const short* w5f   = w4f + 25600;

  grn_main<<<NTOK / ROWS, 64, 0, stream>>>(x, c, wcatf, w1f, w4f, w5f,
                                           b2, b1, b4, b5, gamma, beta,
                                           (float*)d_out);
}

// Round 5
// 272.932 us; speedup vs baseline: 1.2609x; 1.2609x over previous
//
#include <hip/hip_runtime.h>
#include <math.h>

typedef __attribute__((ext_vector_type(8))) short short8;
typedef __attribute__((ext_vector_type(4))) float f32x4;

#define D 160
#define NTOK (256*512)   // 131072 rows
#define ROWS 128         // rows per block; 8 waves x 16 rows

__device__ __forceinline__ short f2bf(float f) {
  union { float f; unsigned u; } v; v.f = f;
  return (short)((v.u + 0x8000u) >> 16);   // round-half-up (=RNE except exact ties)
}

// bf16 eta tile: 128 rows x 160 cols, row stride 192 shorts (24 granules of 16B).
// XOR low 3 bits of granule index with row&7 -> 2-way max bank aliasing (free).
__device__ __forceinline__ int eidx(int row, int col) {
  int g = col >> 3;
  g = (g & ~7) | ((g ^ (row & 7)) & 7);
  return row * 192 + (g << 3) + (col & 7);
}

// Pack weights to bf16 in MFMA B-FRAGMENT ORDER (unchanged):
//   frag f = ks*10 + nt;  element (f, lane, j) = W[n][k],
//   n = nt*16 + (lane&15), k = ks*32 + (lane>>4)*8 + j.
// Frag f occupies bytes [1024f, 1024f+1024), lane's 16B at +lane*16 —
// exactly the global_load_lds wave-linear layout.
__global__ __launch_bounds__(256) void prep_kernel(
    const float* __restrict__ W2, const float* __restrict__ W3,
    const float* __restrict__ W1, const float* __restrict__ W4,
    const float* __restrict__ W5, short* __restrict__ ws) {
  int i = blockIdx.x * 256 + threadIdx.x;
  if (i >= 128000) return;
  if (i < 51200) {
    int f = i >> 9, r = i & 511;
    int lane = r >> 3, j = r & 7;
    int ks = f / 10, nt = f % 10;
    int n = nt * 16 + (lane & 15);
    int k = ks * 32 + (lane >> 4) * 8 + j;
    float v = (k < 160) ? W2[n * 160 + k] : W3[n * 160 + (k - 160)];
    ws[i] = f2bf(v);
  } else {
    int idx = i - 51200;
    int which = idx / 25600;      // 0=W1, 1=W4, 2=W5
    int e = idx % 25600;
    int f = e >> 9, r = e & 511;
    int lane = r >> 3, j = r & 7;
    int ks = f / 10, nt = f % 10;
    int n = nt * 16 + (lane & 15);
    int k = ks * 32 + (lane >> 4) * 8 + j;
    const float* W = (which == 0) ? W1 : (which == 1) ? W4 : W5;
    ws[i] = f2bf(W[n * 160 + k]);
  }
}

#define MFMA(d, a, b) d = __builtin_amdgcn_mfma_f32_16x16x32_bf16(a, b, d, 0, 0, 0)

// async global->LDS, 16B per lane; dest = wave-uniform base + lane*16.
__device__ __forceinline__ void gload16(const void* g, void* l) {
  __builtin_amdgcn_global_load_lds(
      (const __attribute__((address_space(1))) unsigned int*)g,
      (__attribute__((address_space(3))) unsigned int*)l, 16, 0, 0);
}

// Stage one 51200-byte weight buffer (50 frags) cooperatively: 8 waves,
// wave w handles 1KB chunks w, w+8, ... No register destinations -> the
// compiler cannot serialize these; latency is drained at the next barrier.
__device__ __forceinline__ void stage_wave(const short* src, short* dst,
                                           int wave, int lane) {
  for (int g = wave; g < 50; g += 8)
    gload16(src + g * 512 + lane * 8, dst + g * 512 + lane * 8);
}

#define FRAG(buf, f) (*(const short8*)&buf[(f) * 512 + lane * 8])

// 8 waves x 16 rows. Weights flow HBM/L2 -> LDS (phase-ahead, double ring
// buffer) -> regs (dbuf'd ds_read, ~130cy) -> MFMA. 5 barriers/block.
__global__ __launch_bounds__(512, 2) void grn_main(
    const float* __restrict__ x, const float* __restrict__ c,
    const short* __restrict__ wcatf, const short* __restrict__ w1f,
    const short* __restrict__ w4f, const short* __restrict__ w5f,
    const float* __restrict__ b2, const float* __restrict__ b1,
    const float* __restrict__ b4, const float* __restrict__ b5,
    const float* __restrict__ gamma, const float* __restrict__ beta,
    float* __restrict__ out) {
  __shared__ __align__(16) short WB0[25600];       // 51200 B
  __shared__ __align__(16) short WB1[25600];       // 51200 B
  __shared__ __align__(16) short E[ROWS * 192];    // 49152 B

  const int tid  = threadIdx.x;
  const int lane = tid & 63;
  const int wave = tid >> 6;        // 0..7
  const int lr   = lane & 15;
  const int quad = lane >> 4;
  const int m0   = wave * 16;
  const int rowbase = blockIdx.x * ROWS;

  // issue wcat staging first (100KB in flight, covered by A-load/convert)
  stage_wave(wcatf, WB0, wave, lane);           // frags 0..49  (ks 0-4)
  stage_wave(wcatf + 25600, WB1, wave, lane);   // frags 50..99 (ks 5-9)

  // A fragments of [x|c] straight from global, batched then converted
  const float* px = x + (size_t)(rowbase + m0 + lr) * D + quad * 8;
  const float* pc = c + (size_t)(rowbase + m0 + lr) * D + quad * 8;
  f32x4 alo[10], ahi[10];
#pragma unroll
  for (int i = 0; i < 10; ++i) {
    const float* ap = (i < 5) ? (px + i * 32) : (pc + (i - 5) * 32);
    alo[i] = *(const f32x4*)ap;
    ahi[i] = *(const f32x4*)(ap + 4);
  }
  short8 af1[10];
#pragma unroll
  for (int i = 0; i < 10; ++i)
#pragma unroll
    for (int j = 0; j < 4; ++j) {
      af1[i][j]     = f2bf(alo[i][j]);
      af1[i][4 + j] = f2bf(ahi[i][j]);
    }
  float b2s[10];
#pragma unroll
  for (int nt = 0; nt < 10; ++nt) b2s[nt] = b2[nt * 16 + lr];

  __syncthreads();   // sync1: wcat staged, A converted

  // ---------------- phase 1: eta2 = ELU([x|c] @ wcat^T + b2) ----------------
  {
    f32x4 acc[10];
#pragma unroll
    for (int nt = 0; nt < 10; ++nt) acc[nt] = (f32x4){0.f, 0.f, 0.f, 0.f};
    short8 bf[10], bn[10];
#pragma unroll
    for (int nt = 0; nt < 10; ++nt) bf[nt] = FRAG(WB0, nt);
#pragma unroll
    for (int ks = 0; ks < 5; ++ks) {
#pragma unroll
      for (int nt = 0; nt < 10; ++nt)
        bn[nt] = (ks < 4) ? FRAG(WB0, (ks + 1) * 10 + nt) : FRAG(WB1, nt);
#pragma unroll
      for (int nt = 0; nt < 10; ++nt) MFMA(acc[nt], af1[ks], bf[nt]);
#pragma unroll
      for (int nt = 0; nt < 10; ++nt) bf[nt] = bn[nt];
    }

    __syncthreads();                      // sync2: all WB0 reads retired
    stage_wave(w1f, WB0, wave, lane);     // W1 -> WB0 (covered by 1b+epilogue)

#pragma unroll
    for (int k2 = 0; k2 < 5; ++k2) {
      if (k2 < 4) {
#pragma unroll
        for (int nt = 0; nt < 10; ++nt) bn[nt] = FRAG(WB1, (k2 + 1) * 10 + nt);
      }
#pragma unroll
      for (int nt = 0; nt < 10; ++nt) MFMA(acc[nt], af1[5 + k2], bf[nt]);
      if (k2 < 4) {
#pragma unroll
        for (int nt = 0; nt < 10; ++nt) bf[nt] = bn[nt];
      }
    }
#pragma unroll
    for (int nt = 0; nt < 10; ++nt)
#pragma unroll
      for (int r = 0; r < 4; ++r) {
        float v = acc[nt][r] + b2s[nt];
        v = v > 0.f ? v : (__expf(v) - 1.f);   // ELU
        E[eidx(m0 + quad * 4 + r, nt * 16 + lr)] = f2bf(v);
      }
  }

  __syncthreads();                        // sync3: W1 visible, WB1 free
  stage_wave(w4f, WB1, wave, lane);       // W4 -> WB1 (covered by phase 2)

  // ---------------- phase 2: eta1 = eta2 @ W1^T + b1 (in-place) -------------
  {
    f32x4 acc[10];
#pragma unroll
    for (int nt = 0; nt < 10; ++nt) acc[nt] = (f32x4){0.f, 0.f, 0.f, 0.f};
    float b1s[10];
#pragma unroll
    for (int nt = 0; nt < 10; ++nt) b1s[nt] = b1[nt * 16 + lr];

    short8 bf[10], bn[10];
#pragma unroll
    for (int nt = 0; nt < 10; ++nt) bf[nt] = FRAG(WB0, nt);
    short8 af = *(const short8*)&E[eidx(m0 + lr, quad * 8)];
    short8 afn;
#pragma unroll
    for (int ks = 0; ks < 5; ++ks) {
      if (ks < 4) {
        afn = *(const short8*)&E[eidx(m0 + lr, (ks + 1) * 32 + quad * 8)];
#pragma unroll
        for (int nt = 0; nt < 10; ++nt) bn[nt] = FRAG(WB0, (ks + 1) * 10 + nt);
      }
#pragma unroll
      for (int nt = 0; nt < 10; ++nt) MFMA(acc[nt], af, bf[nt]);
      if (ks < 4) {
        af = afn;
#pragma unroll
        for (int nt = 0; nt < 10; ++nt) bf[nt] = bn[nt];
      }
    }
#pragma unroll
    for (int nt = 0; nt < 10; ++nt)
#pragma unroll
      for (int r = 0; r < 4; ++r) {
        float v = acc[nt][r] + b1s[nt];
        E[eidx(m0 + quad * 4 + r, nt * 16 + lr)] = f2bf(v);
      }
  }

  __syncthreads();                        // sync4: W4 visible, WB0 free
  stage_wave(w5f, WB0, wave, lane);       // W5 -> WB0 (covered by phase 3g)

  // ---------------- phase 3: gate then value, GLU + residual + LN -----------
  f32x4 ag[10], av[10];
#pragma unroll
  for (int nt = 0; nt < 10; ++nt) {
    ag[nt] = (f32x4){0.f, 0.f, 0.f, 0.f};
    av[nt] = (f32x4){0.f, 0.f, 0.f, 0.f};
  }
  float b4s[10], b5s[10];
#pragma unroll
  for (int nt = 0; nt < 10; ++nt) {
    b4s[nt] = b4[nt * 16 + lr];
    b5s[nt] = b5[nt * 16 + lr];
  }
  {   // gate from WB1 (W4)
    short8 bf[10], bn[10];
#pragma unroll
    for (int nt = 0; nt < 10; ++nt) bf[nt] = FRAG(WB1, nt);
    short8 af = *(const short8*)&E[eidx(m0 + lr, quad * 8)];
    short8 afn;
#pragma unroll
    for (int ks = 0; ks < 5; ++ks) {
      if (ks < 4) {
        afn = *(const short8*)&E[eidx(m0 + lr, (ks + 1) * 32 + quad * 8)];
#pragma unroll
        for (int nt = 0; nt < 10; ++nt) bn[nt] = FRAG(WB1, (ks + 1) * 10 + nt);
      }
#pragma unroll
      for (int nt = 0; nt < 10; ++nt) MFMA(ag[nt], af, bf[nt]);
      if (ks < 4) {
        af = afn;
#pragma unroll
        for (int nt = 0; nt < 10; ++nt) bf[nt] = bn[nt];
      }
    }
  }

  __syncthreads();                        // sync5: W5 visible

  // residual x batch-issued; latency hides under the value MFMA rounds
  float xr[10][4];
#pragma unroll
  for (int nt = 0; nt < 10; ++nt)
#pragma unroll
    for (int r = 0; r < 4; ++r)
      xr[nt][r] = x[(size_t)(rowbase + m0 + quad * 4 + r) * D + nt * 16 + lr];

  {   // value from WB0 (W5)
    short8 bf[10], bn[10];
#pragma unroll
    for (int nt = 0; nt < 10; ++nt) bf[nt] = FRAG(WB0, nt);
    short8 af = *(const short8*)&E[eidx(m0 + lr, quad * 8)];
    short8 afn;
#pragma unroll
    for (int ks = 0; ks < 5; ++ks) {
      if (ks < 4) {
        afn = *(const short8*)&E[eidx(m0 + lr, (ks + 1) * 32 + quad * 8)];
#pragma unroll
        for (int nt = 0; nt < 10; ++nt) bn[nt] = FRAG(WB0, (ks + 1) * 10 + nt);
      }
#pragma unroll
      for (int nt = 0; nt < 10; ++nt) MFMA(av[nt], af, bf[nt]);
      if (ks < 4) {
        af = afn;
#pragma unroll
        for (int nt = 0; nt < 10; ++nt) bf[nt] = bn[nt];
      }
    }
  }

  float y[10][4];
  float sum[4] = {0.f, 0.f, 0.f, 0.f};
  float ssq[4] = {0.f, 0.f, 0.f, 0.f};
#pragma unroll
  for (int nt = 0; nt < 10; ++nt)
#pragma unroll
    for (int r = 0; r < 4; ++r) {
      float g = ag[nt][r] + b4s[nt];
      float v = av[nt][r] + b5s[nt];
      float glu = v * __builtin_amdgcn_rcpf(1.f + __expf(-g));
      float yy = xr[nt][r] + glu;
      y[nt][r] = yy;
      sum[r] += yy;
      ssq[r] += yy * yy;
    }
#pragma unroll
  for (int off = 1; off < 16; off <<= 1)
#pragma unroll
    for (int r = 0; r < 4; ++r) {
      sum[r] += __shfl_xor(sum[r], off, 64);
      ssq[r] += __shfl_xor(ssq[r], off, 64);
    }
  float mean[4], rstd[4];
#pragma unroll
  for (int r = 0; r < 4; ++r) {
    mean[r] = sum[r] * (1.f / 160.f);
    float var = ssq[r] * (1.f / 160.f) - mean[r] * mean[r];
    rstd[r] = __builtin_amdgcn_rsqf(var + 1e-5f);
  }
#pragma unroll
  for (int nt = 0; nt < 10; ++nt) {
    int col = nt * 16 + lr;
    float ga = gamma[col];
    float be = beta[col];
#pragma unroll
    for (int r = 0; r < 4; ++r) {
      size_t row = (size_t)(rowbase + m0 + quad * 4 + r);
      out[row * D + col] = (y[nt][r] - mean[r]) * rstd[r] * ga + be;
    }
  }
}

extern "C" void kernel_launch(void* const* d_in, const int* in_sizes, int n_in,
                              void* d_out, int out_size, void* d_ws, size_t ws_size,
                              hipStream_t stream) {
  const float* x     = (const float*)d_in[0];
  const float* c     = (const float*)d_in[1];
  const float* W2    = (const float*)d_in[2];
  const float* b2    = (const float*)d_in[3];
  const float* W3    = (const float*)d_in[4];
  const float* W1    = (const float*)d_in[5];
  const float* b1    = (const float*)d_in[6];
  const float* W4    = (const float*)d_in[7];
  const float* b4    = (const float*)d_in[8];
  const float* W5    = (const float*)d_in[9];
  const float* b5    = (const float*)d_in[10];
  const float* gamma = (const float*)d_in[11];
  const float* beta  = (const float*)d_in[12];

  short* ws = (short*)d_ws;   // 256000 B; re-packed every launch
  prep_kernel<<<500, 256, 0, stream>>>(W2, W3, W1, W4, W5, ws);

  const short* wcatf = ws;
  const short* w1f   = ws + 51200;
  const short* w4f   = w1f + 25600;
  const short* w5f   = w4f + 25600;

  grn_main<<<NTOK / ROWS, 512, 0, stream>>>(x, c, wcatf, w1f, w4f, w5f,
                                            b2, b1, b4, b5, gamma, beta,
                                            (float*)d_out);
}